// Round 2
// baseline (761.586 us; speedup 1.0000x reference)
//
#include <hip/hip_runtime.h>

// Discounted cumulative return y[t] = r[t] + a[t]*y[t+1] (a = terminal?0:0.99)
// Single-pass reverse affine scan with decoupled lookback (rocPRIM-style).
//
// Tile descriptors: two 64-bit words per tile, each packing {flag:32, f32:32}.
//   w1 = {PARTIAL, A}   (written once)
//   w2 = {PARTIAL, B} then {COMPLETE, v}   (release stores; readers acquire)
// A COMPLETE predecessor acts as the constant affine fn (A=0, B=v), which
// absorbs all earlier tiles in the ordered wave reduce.

constexpr int   TPB  = 256;
constexpr int   IPT  = 16;
constexpr int   TILE = TPB * IPT;     // 4096
constexpr float DISC = 0.99f;

#define FLAG_INVALID  0u
#define FLAG_PARTIAL  1u
#define FLAG_COMPLETE 2u

__device__ __forceinline__ unsigned long long pack_desc(unsigned f, float v) {
    return ((unsigned long long)f << 32) | (unsigned long long)__float_as_uint(v);
}

// Inclusive block scan of affine fns in scan order (thread 0 applied first).
__device__ __forceinline__ void block_scan_inc(float& A, float& B,
                                               float* sA, float* sB, int t) {
    sA[t] = A; sB[t] = B;
    __syncthreads();
    #pragma unroll
    for (int off = 1; off < TPB; off <<= 1) {
        float pa = 1.f, pb = 0.f;
        if (t >= off) { pa = sA[t - off]; pb = sB[t - off]; }
        __syncthreads();
        B = A * pb + B;          // self o prev
        A = A * pa;
        sA[t] = A; sB[t] = B;
        __syncthreads();
    }
}

__global__ __launch_bounds__(TPB) void k_onepass(
        const int* __restrict__ term, const float* __restrict__ rew,
        float* __restrict__ out,
        unsigned long long* __restrict__ w1, unsigned long long* __restrict__ w2,
        unsigned* __restrict__ counter,
        int numTiles, long long T) {
    __shared__ float sA[TPB], sB[TPB];
    __shared__ float s_Ablk, s_Bblk, s_yin;
    __shared__ unsigned s_rank;

    const int t = threadIdx.x;
    if (t == 0) s_rank = atomicAdd(counter, 1u);   // dispatch-ordered rank
    __syncthreads();
    const int rank = (int)s_rank;
    const int g = numTiles - 1 - rank;             // scan runs from high tiles down

    const long long tileBase = (long long)g * TILE;
    const long long base = tileBase + (long long)(TPB - 1 - t) * IPT;

    float r[IPT], a[IPT];
    const bool fast = (base + IPT <= T);
    if (fast) {
        #pragma unroll
        for (int q = 0; q < IPT / 4; ++q) {
            float4 rv = ((const float4*)(rew + base))[q];
            int4   tv = ((const int4*)(term + base))[q];
            r[4*q+0] = rv.x; r[4*q+1] = rv.y; r[4*q+2] = rv.z; r[4*q+3] = rv.w;
            a[4*q+0] = tv.x ? 0.f : DISC;
            a[4*q+1] = tv.y ? 0.f : DISC;
            a[4*q+2] = tv.z ? 0.f : DISC;
            a[4*q+3] = tv.w ? 0.f : DISC;
        }
    } else {
        #pragma unroll
        for (int k = 0; k < IPT; ++k) {
            long long i = base + k;
            if (i < T) { r[k] = rew[i]; a[k] = term[i] ? 0.f : DISC; }
            else       { r[k] = 0.f;   a[k] = 1.f; }
        }
    }

    // local compose high->low index
    float A = 1.f, B = 0.f;
    #pragma unroll
    for (int k = IPT - 1; k >= 0; --k) { B = a[k] * B + r[k]; A = a[k] * A; }

    block_scan_inc(A, B, sA, sB, t);

    // publish PARTIAL asap (thread TPB-1 holds the block aggregate)
    if (t == TPB - 1) {
        s_Ablk = A; s_Bblk = B;
        __hip_atomic_store(&w1[rank], pack_desc(FLAG_PARTIAL, A),
                           __ATOMIC_RELAXED, __HIP_MEMORY_SCOPE_AGENT);
        __hip_atomic_store(&w2[rank], pack_desc(FLAG_PARTIAL, B),
                           __ATOMIC_RELEASE, __HIP_MEMORY_SCOPE_AGENT);
    }

    // exclusive prefix over threads 0..t-1 (higher global indices)
    float EA = 1.f, EB = 0.f;
    if (t > 0) { EA = sA[t - 1]; EB = sB[t - 1]; }
    __syncthreads();   // s_Ablk/s_Bblk visible; sA/sB reads done

    // ---- wave-0 parallel lookback ----
    if (t < 64) {
        float accA = 1.f, accB = 0.f;
        bool done = false;
        float yin = 0.f;
        for (int round = 0; !done; ++round) {
            const int j = rank - 1 - t - round * 64;
            float fA, fB; bool comp;
            if (j < 0) {                       // before tile 0 of scan: y = 0
                fA = 0.f; fB = 0.f; comp = true;
            } else {
                unsigned long long v2 = __hip_atomic_load(
                    &w2[j], __ATOMIC_ACQUIRE, __HIP_MEMORY_SCOPE_AGENT);
                while ((unsigned)(v2 >> 32) == FLAG_INVALID) {
                    __builtin_amdgcn_s_sleep(1);
                    v2 = __hip_atomic_load(&w2[j], __ATOMIC_ACQUIRE,
                                           __HIP_MEMORY_SCOPE_AGENT);
                }
                if ((unsigned)(v2 >> 32) == FLAG_COMPLETE) {
                    comp = true; fA = 0.f; fB = __uint_as_float((unsigned)v2);
                } else {
                    unsigned long long v1 = __hip_atomic_load(
                        &w1[j], __ATOMIC_RELAXED, __HIP_MEMORY_SCOPE_AGENT);
                    comp = false;
                    fA = __uint_as_float((unsigned)v1);
                    fB = __uint_as_float((unsigned)v2);
                }
            }
            // ordered reduce: lane0 <- G_0 o G_1 o ... o G_63
            #pragma unroll
            for (int off = 1; off < 64; off <<= 1) {
                float oA = __shfl_down(fA, off, 64);
                float oB = __shfl_down(fB, off, 64);
                if (t + off < 64) { fB = fA * oB + fB; fA = fA * oA; }
            }
            const bool anyComplete = (__ballot(comp) != 0ull);  // wave-uniform
            if (t == 0) {
                if (anyComplete) { yin = accA * fB + accB; }
                else             { accB = accA * fB + accB; accA = accA * fA; }
            }
            done = anyComplete;
        }
        if (t == 0) {
            s_yin = yin;
            const float v = s_Ablk * yin + s_Bblk;   // this tile's outgoing y
            __hip_atomic_store(&w2[rank], pack_desc(FLAG_COMPLETE, v),
                               __ATOMIC_RELEASE, __HIP_MEMORY_SCOPE_AGENT);
        }
    }
    __syncthreads();
    const float yin = s_yin;

    // apply: y at this thread's high edge, then walk down
    float y = EA * yin + EB;
    float yv[IPT];
    #pragma unroll
    for (int k = IPT - 1; k >= 0; --k) { y = a[k] * y + r[k]; yv[k] = y; }

    if (fast) {
        #pragma unroll
        for (int q = 0; q < IPT / 4; ++q) {
            ((float4*)(out + base))[q] =
                make_float4(yv[4*q+0], yv[4*q+1], yv[4*q+2], yv[4*q+3]);
        }
    } else {
        #pragma unroll
        for (int k = 0; k < IPT; ++k) {
            long long i = base + k;
            if (i < T) out[i] = yv[k];
        }
    }
}

extern "C" void kernel_launch(void* const* d_in, const int* in_sizes, int n_in,
                              void* d_out, int out_size, void* d_ws, size_t ws_size,
                              hipStream_t stream) {
    const int*   term = (const int*)d_in[0];
    const float* rew  = (const float*)d_in[1];
    float*       out  = (float*)d_out;

    const long long T = (long long)in_sizes[1];
    const int numTiles = (int)((T + TILE - 1) / TILE);

    unsigned long long* w1 = (unsigned long long*)d_ws;
    unsigned long long* w2 = w1 + numTiles;
    unsigned* counter = (unsigned*)(w2 + numTiles);

    const size_t ctrlBytes = (size_t)numTiles * 16 + 64;
    hipMemsetAsync(d_ws, 0, ctrlBytes, stream);   // flags INVALID, counter 0

    k_onepass<<<numTiles, TPB, 0, stream>>>(term, rew, out, w1, w2, counter,
                                            numTiles, T);
}

// Round 3
// 215.530 us; speedup vs baseline: 3.5336x; 3.5336x over previous
//
#include <hip/hip_runtime.h>

// Discounted cumulative return y[t] = r[t] + a[t]*y[t+1], a[t]=terminal[t]?0:0.99
// 3-pass reduce-then-scan. Round-3: IPT=4 fully-coalesced loads, shuffle-based
// block suffix-scan (2 barriers), float2 tile aggregates.
//
// Affine fn F(x)=A*x+B over index range [lo,hi] maps y[hi+1]->y[lo].
// Compose (outer=lower indices): (A1,B1)o(A2,B2) = (A1*A2, A1*B2+B1).

constexpr int   TPB  = 256;
constexpr int   IPT  = 4;
constexpr int   TILE = TPB * IPT;     // 1024
constexpr float DISC = 0.99f;

// Wave-level inclusive SUFFIX scan in thread order: after this, lane l holds
// L_l o L_{l+1} o ... o L_63.
__device__ __forceinline__ void wave_suffix_scan(float& A, float& B, int lane) {
    #pragma unroll
    for (int off = 1; off < 64; off <<= 1) {
        float oA = __shfl_down(A, off, 64);
        float oB = __shfl_down(B, off, 64);
        if (lane + off < 64) { B = A * oB + B; A = A * oA; }
    }
}

// K1: per-tile aggregate (A,B) -> agg[blockIdx].
__global__ __launch_bounds__(TPB) void k_agg(const int* __restrict__ term,
                                             const float* __restrict__ rew,
                                             float2* __restrict__ agg,
                                             long long T) {
    __shared__ float2 sW[TPB / 64];
    const int t = threadIdx.x;
    const int lane = t & 63, wav = t >> 6;
    const long long base = (long long)blockIdx.x * TILE + (long long)t * IPT;

    float r[IPT], a[IPT];
    if (base + IPT <= T) {
        float4 rv = *(const float4*)(rew + base);
        int4   tv = *(const int4*)(term + base);
        r[0]=rv.x; r[1]=rv.y; r[2]=rv.z; r[3]=rv.w;
        a[0]=tv.x?0.f:DISC; a[1]=tv.y?0.f:DISC; a[2]=tv.z?0.f:DISC; a[3]=tv.w?0.f:DISC;
    } else {
        #pragma unroll
        for (int k = 0; k < IPT; ++k) {
            long long i = base + k;
            if (i < T) { r[k]=rew[i]; a[k]=term[i]?0.f:DISC; }
            else       { r[k]=0.f;   a[k]=1.f; }
        }
    }

    float A = 1.f, B = 0.f;
    #pragma unroll
    for (int k = IPT - 1; k >= 0; --k) { B = a[k]*B + r[k]; A = a[k]*A; }

    wave_suffix_scan(A, B, lane);             // lane0 = wave aggregate
    if (lane == 0) sW[wav] = make_float2(A, B);
    __syncthreads();
    if (t == 0) {
        float2 g = sW[0];
        #pragma unroll
        for (int w = 1; w < TPB / 64; ++w) {
            float2 h = sW[w];
            g.y = g.x * h.y + g.y; g.x = g.x * h.x;
        }
        agg[blockIdx.x] = g;
    }
}

// K2: single block; per-tile incoming value yin[g] = (T_{g+1}o...oT_{N-1})(0).
__global__ __launch_bounds__(TPB) void k_mid(const float2* __restrict__ agg,
                                             float* __restrict__ yin,
                                             int numTiles) {
    __shared__ float2 sW[TPB / 64];
    const int t = threadIdx.x;
    const int lane = t & 63, wav = t >> 6;
    const int cpt = (numTiles + TPB - 1) / TPB;
    const int lo = t * cpt;

    // local aggregate over tiles [lo, lo+cpt), composed descending
    float A = 1.f, B = 0.f;
    for (int k = cpt - 1; k >= 0; --k) {
        int g = lo + k;
        if (g < numTiles) {
            float2 v = agg[g];
            B = v.x * B + v.y; A = v.x * A;
        }
    }

    float IA = A, IB = B;
    wave_suffix_scan(IA, IB, lane);
    if (lane == 0) sW[wav] = make_float2(IA, IB);
    __syncthreads();

    float EWA = 1.f, EWB = 0.f;               // exclusive over higher waves
    #pragma unroll
    for (int w = 0; w < TPB / 64; ++w)
        if (w > wav) { float2 h = sW[w]; EWB = EWA*h.y + EWB; EWA = EWA*h.x; }

    float EA = __shfl_down(IA, 1, 64);        // within-wave exclusive
    float EB = __shfl_down(IB, 1, 64);
    if (lane == 63) { EA = 1.f; EB = 0.f; }

    // v = value entering highest tile of this thread's chunk; FINAL_REWARD=0
    float x1 = EWB;                           // EW applied to 0
    float v  = EA * x1 + EB;                  // E^wave applied
    for (int k = cpt - 1; k >= 0; --k) {
        int g = lo + k;
        if (g < numTiles) {
            yin[g] = v;
            float2 q = agg[g];
            v = q.x * v + q.y;
        }
    }
}

// K3: re-read inputs, apply tile prefix, write outputs.
__global__ __launch_bounds__(TPB) void k_apply(const int* __restrict__ term,
                                               const float* __restrict__ rew,
                                               const float* __restrict__ yin,
                                               float* __restrict__ out,
                                               long long T) {
    __shared__ float2 sW[TPB / 64];
    const int t = threadIdx.x;
    const int lane = t & 63, wav = t >> 6;
    const long long base = (long long)blockIdx.x * TILE + (long long)t * IPT;

    float r[IPT], a[IPT];
    const bool fast = (base + IPT <= T);
    if (fast) {
        float4 rv = *(const float4*)(rew + base);
        int4   tv = *(const int4*)(term + base);
        r[0]=rv.x; r[1]=rv.y; r[2]=rv.z; r[3]=rv.w;
        a[0]=tv.x?0.f:DISC; a[1]=tv.y?0.f:DISC; a[2]=tv.z?0.f:DISC; a[3]=tv.w?0.f:DISC;
    } else {
        #pragma unroll
        for (int k = 0; k < IPT; ++k) {
            long long i = base + k;
            if (i < T) { r[k]=rew[i]; a[k]=term[i]?0.f:DISC; }
            else       { r[k]=0.f;   a[k]=1.f; }
        }
    }

    float A = 1.f, B = 0.f;
    #pragma unroll
    for (int k = IPT - 1; k >= 0; --k) { B = a[k]*B + r[k]; A = a[k]*A; }

    float IA = A, IB = B;
    wave_suffix_scan(IA, IB, lane);
    if (lane == 0) sW[wav] = make_float2(IA, IB);
    __syncthreads();

    float EWA = 1.f, EWB = 0.f;
    #pragma unroll
    for (int w = 0; w < TPB / 64; ++w)
        if (w > wav) { float2 h = sW[w]; EWB = EWA*h.y + EWB; EWA = EWA*h.x; }

    float EA = __shfl_down(IA, 1, 64);
    float EB = __shfl_down(IB, 1, 64);
    if (lane == 63) { EA = 1.f; EB = 0.f; }

    const float yt = yin[blockIdx.x];         // y entering this tile from above
    float x1 = EWA * yt + EWB;                // higher waves applied
    float y  = EA * x1 + EB;                  // higher lanes applied -> y at base+IPT

    float yv[IPT];
    #pragma unroll
    for (int k = IPT - 1; k >= 0; --k) { y = a[k]*y + r[k]; yv[k] = y; }

    if (fast) {
        *(float4*)(out + base) = make_float4(yv[0], yv[1], yv[2], yv[3]);
    } else {
        #pragma unroll
        for (int k = 0; k < IPT; ++k) {
            long long i = base + k;
            if (i < T) out[i] = yv[k];
        }
    }
}

extern "C" void kernel_launch(void* const* d_in, const int* in_sizes, int n_in,
                              void* d_out, int out_size, void* d_ws, size_t ws_size,
                              hipStream_t stream) {
    const int*   term = (const int*)d_in[0];
    const float* rew  = (const float*)d_in[1];
    float*       out  = (float*)d_out;

    const long long T = (long long)in_sizes[1];
    const int numTiles = (int)((T + TILE - 1) / TILE);   // 16384 for T=2^24

    float2* agg = (float2*)d_ws;
    float*  yin = (float*)(agg + numTiles);

    k_agg  <<<numTiles, TPB, 0, stream>>>(term, rew, agg, T);
    k_mid  <<<1,        TPB, 0, stream>>>(agg, yin, numTiles);
    k_apply<<<numTiles, TPB, 0, stream>>>(term, rew, yin, out, T);
}

// Round 6
// 183.290 us; speedup vs baseline: 4.1551x; 1.1759x over previous
//
#include <hip/hip_runtime.h>

// Discounted cumulative return y[t] = r[t] + a[t]*y[t+1], a[t]=terminal[t]?0:0.99
// Round 6: 2-pass "local scan + sparse tail fix".
//   K1: in-block scan with y_in=0 -> out, per-block aggregate (A,B) + last
//       terminal index. Inputs read once.
//   K2: per-block compose of aggregates above -> y_in; correction
//       out[i] += 0.99^(hi+1-i) * y_in applies ONLY to i past the block's last
//       terminal (elsewhere the a=0 factor kills it) -> ~12.5% of elements.
//
// Affine F(x)=A*x+B maps y[hi+1]->y[lo]; compose outer = lower indices:
// (A1,B1)o(A2,B2) = (A1*A2, A1*B2+B1).

constexpr int   TPB  = 256;
constexpr int   IPT  = 32;
constexpr int   TILE = TPB * IPT;          // 8192 elems per block
constexpr float DISC = 0.99f;
constexpr float L2DISC = -0.0144995696f;   // log2(0.99)

// Inclusive wave SUFFIX scan: lane l ends with F_l o F_{l+1} o ... o F_63.
__device__ __forceinline__ void wave_suffix_scan(float& A, float& B, int lane) {
    #pragma unroll
    for (int off = 1; off < 64; off <<= 1) {
        float oA = __shfl_down(A, off, 64);
        float oB = __shfl_down(B, off, 64);
        if (lane + off < 64) { B = A * oB + B; A = A * oA; }
    }
}

// K1: local scan (y_in = 0) -> out; write agg[b] and lastT[b].
__global__ __launch_bounds__(TPB) void k_local(
        const int* __restrict__ term, const float* __restrict__ rew,
        float* __restrict__ out, float2* __restrict__ agg,
        int* __restrict__ lastT, long long T) {
    __shared__ float2 sWA[TPB / 64];
    __shared__ int    sLast[TPB / 64];

    const int t = threadIdx.x;
    const int lane = t & 63, wav = t >> 6;
    const int b = blockIdx.x;
    const long long lo   = (long long)b * TILE;
    const long long base = lo + (long long)t * IPT;
    const bool fast = (base + IPT <= T);

    float r[IPT];
    unsigned mask = 0;
    if (fast) {
        const float4* rp = (const float4*)(rew + base);
        const int4*   tp = (const int4*)(term + base);
        #pragma unroll
        for (int q = 0; q < IPT / 4; ++q) {
            float4 rv = rp[q];
            int4   tv = tp[q];
            r[4*q+0] = rv.x; r[4*q+1] = rv.y; r[4*q+2] = rv.z; r[4*q+3] = rv.w;
            mask |= (tv.x ? 1u : 0u) << (4*q+0);
            mask |= (tv.y ? 1u : 0u) << (4*q+1);
            mask |= (tv.z ? 1u : 0u) << (4*q+2);
            mask |= (tv.w ? 1u : 0u) << (4*q+3);
        }
    } else {
        #pragma unroll
        for (int k = 0; k < IPT; ++k) {
            long long i = base + k;
            if (i < T) { r[k] = rew[i]; mask |= (term[i] ? 1u : 0u) << k; }
            else       { r[k] = 0.f; }
        }
    }

    // thread-local compose, high->low index (padding uses a=1 identity)
    float A = 1.f, B = 0.f;
    #pragma unroll
    for (int k = IPT - 1; k >= 0; --k) {
        float ak = ((mask >> k) & 1u) ? 0.f : DISC;
        if (!fast && base + k >= T) ak = 1.f;
        B = ak * B + r[k]; A = ak * A;
    }

    float IA = A, IB = B;
    wave_suffix_scan(IA, IB, lane);

    // per-thread last terminal (global index), wave max-reduce
    int myLast = mask ? (int)(base + (31 - __clz(mask))) : -1;
    #pragma unroll
    for (int off = 32; off > 0; off >>= 1)
        myLast = max(myLast, __shfl_down(myLast, off, 64));

    if (lane == 0) { sWA[wav] = make_float2(IA, IB); sLast[wav] = myLast; }
    __syncthreads();

    if (t == 0) {
        float2 g = sWA[0];                 // wave 0 outermost (lowest idx)
        int lt = sLast[0];
        #pragma unroll
        for (int w = 1; w < TPB / 64; ++w) {
            float2 h = sWA[w];
            g.y = g.x * h.y + g.y; g.x = g.x * h.x;
            lt = max(lt, sLast[w]);
        }
        agg[b] = g;
        lastT[b] = max(lt, (int)lo - 1);   // lo-1 == "no terminal in block"
    }

    // exclusive over higher waves within the block
    float EWA = 1.f, EWB = 0.f;
    #pragma unroll
    for (int w = 0; w < TPB / 64; ++w)
        if (w > wav) { float2 h = sWA[w]; EWB = EWA*h.y + EWB; EWA = EWA*h.x; }

    // exclusive over higher lanes within the wave
    float EA = __shfl_down(IA, 1, 64);
    float EB = __shfl_down(IB, 1, 64);
    if (lane == 63) { EA = 1.f; EB = 0.f; }

    float y = EA * EWB + EB;               // y_in = 0: y at base + IPT

    #pragma unroll
    for (int k = IPT - 1; k >= 0; --k) {
        float ak = ((mask >> k) & 1u) ? 0.f : DISC;
        if (!fast && base + k >= T) ak = 1.f;
        y = ak * y + r[k]; r[k] = y;
    }

    if (fast) {
        float4* op = (float4*)(out + base);
        #pragma unroll
        for (int q = 0; q < IPT / 4; ++q)
            op[q] = make_float4(r[4*q+0], r[4*q+1], r[4*q+2], r[4*q+3]);
    } else {
        #pragma unroll
        for (int k = 0; k < IPT; ++k) {
            long long i = base + k;
            if (i < T) out[i] = r[k];
        }
    }
}

// K2: per-block y_in from aggregates above, then sparse tail correction.
__global__ __launch_bounds__(TPB) void k_fix(
        const float2* __restrict__ agg, const int* __restrict__ lastT,
        float* __restrict__ out, int numBlocks, long long T) {
    __shared__ float2 sWB[TPB / 64];

    const int t = threadIdx.x;
    const int lane = t & 63, wav = t >> 6;
    const int b = blockIdx.x;

    // compose aggregates of blocks above b (blocks <= b act as identity)
    const int cpt = (numBlocks + TPB - 1) / TPB;     // 8 for 2048
    float VA = 1.f, VB = 0.f;
    #pragma unroll
    for (int k = cpt - 1; k >= 0; --k) {             // descending g: inner first
        int g = t * cpt + k;
        if (g > b && g < numBlocks) {
            float2 q = agg[g];
            VB = q.x * VB + q.y; VA = q.x * VA;
        }
    }
    wave_suffix_scan(VA, VB, lane);
    if (lane == 0) sWB[wav] = make_float2(VA, VB);
    __syncthreads();

    float FA = sWB[0].x, FB = sWB[0].y;              // wave 0 outermost
    #pragma unroll
    for (int w = 1; w < TPB / 64; ++w) {
        float2 h = sWB[w];
        FB = FA * h.y + FB; FA = FA * h.x;
    }
    const float yin = FB;                            // y entering block b (x=0)
    if (yin == 0.f) return;

    const long long lo = (long long)b * TILE;
    const long long hi = min(lo + TILE, T) - 1;
    const long long start = (long long)lastT[b] + 1; // >= lo by construction

    for (long long i = start + t; i <= hi; i += TPB) {
        float d = (float)(int)(hi + 1 - i);
        out[i] += exp2f(d * L2DISC) * yin;
    }
}

extern "C" void kernel_launch(void* const* d_in, const int* in_sizes, int n_in,
                              void* d_out, int out_size, void* d_ws, size_t ws_size,
                              hipStream_t stream) {
    const int*   term = (const int*)d_in[0];
    const float* rew  = (const float*)d_in[1];
    float*       out  = (float*)d_out;

    const long long T = (long long)in_sizes[1];
    const int numBlocks = (int)((T + TILE - 1) / TILE);   // 2048 for T=2^24

    float2* agg   = (float2*)d_ws;
    int*    lastT = (int*)(agg + numBlocks);

    k_local<<<numBlocks, TPB, 0, stream>>>(term, rew, out, agg, lastT, T);
    k_fix  <<<numBlocks, TPB, 0, stream>>>(agg, lastT, out, numBlocks, T);
}

// Round 7
// 178.615 us; speedup vs baseline: 4.2638x; 1.0262x over previous
//
#include <hip/hip_runtime.h>

// Discounted cumulative return y[t] = r[t] + a[t]*y[t+1], a[t]=terminal[t]?0:0.99
// Round 7: K1 software-pipelined into 4 chunks/block so global stores of chunk c
// overlap global loads of chunk c-1 (R6 showed read and write phases were
// serializing: 2.86 TB/s combined vs 3.15 TB/s per-direction cap).
//   K1: in-block scan with y_in=0 -> out, per-block aggregate (A,B) + last
//       terminal index. Inputs read once.
//   K2: per-block compose of aggregates above -> y_in; correction
//       out[i] += 0.99^(hi+1-i) * y_in only past the block's last terminal.
//
// Affine F(x)=A*x+B maps y[hi+1]->y[lo]; compose outer = lower indices:
// (A1,B1)o(A2,B2) = (A1*A2, A1*B2+B1).

constexpr int   TPB   = 256;
constexpr int   IPTC  = 8;               // elems per thread per chunk
constexpr int   NCH   = 4;               // chunks per block (pipelined)
constexpr int   CHUNK = TPB * IPTC;      // 2048
constexpr int   TILE  = CHUNK * NCH;     // 8192 elems per block
constexpr float DISC  = 0.99f;
constexpr float L2DISC = -0.0144995696f; // log2(0.99)

// Inclusive wave SUFFIX scan: lane l ends with F_l o F_{l+1} o ... o F_63.
__device__ __forceinline__ void wave_suffix_scan(float& A, float& B, int lane) {
    #pragma unroll
    for (int off = 1; off < 64; off <<= 1) {
        float oA = __shfl_down(A, off, 64);
        float oB = __shfl_down(B, off, 64);
        if (lane + off < 64) { B = A * oB + B; A = A * oA; }
    }
}

// K1: local scan (y_in = 0) -> out; write agg[b] and lastT[b].
__global__ __launch_bounds__(TPB) void k_local(
        const int* __restrict__ term, const float* __restrict__ rew,
        float* __restrict__ out, float2* __restrict__ agg,
        int* __restrict__ lastT, long long T) {
    __shared__ float2 sWA[TPB / 64];
    __shared__ int    sLast[TPB / 64];

    const int t = threadIdx.x;
    const int lane = t & 63, wav = t >> 6;
    const int b = blockIdx.x;
    const long long lo = (long long)b * TILE;
    const bool fastblk = (lo + TILE <= T);

    float At = 1.f, Bt = 0.f;   // block aggregate over processed (higher) chunks
    int   lt = -1;              // last terminal global index in block

    if (fastblk) {
        float4 bR[2][IPTC / 4];
        int4   bT[2][IPTC / 4];

        // prefetch highest chunk
        {
            const long long base = lo + (long long)(NCH - 1) * CHUNK
                                      + (long long)t * IPTC;
            const float4* rp = (const float4*)(rew + base);
            const int4*   tp = (const int4*)(term + base);
            #pragma unroll
            for (int q = 0; q < IPTC / 4; ++q) {
                bR[(NCH - 1) & 1][q] = rp[q];
                bT[(NCH - 1) & 1][q] = tp[q];
            }
        }

        #pragma unroll
        for (int c = NCH - 1; c >= 0; --c) {
            // issue next (lower) chunk's loads before computing this one
            if (c > 0) {
                const long long nbase = lo + (long long)(c - 1) * CHUNK
                                           + (long long)t * IPTC;
                const float4* rp = (const float4*)(rew + nbase);
                const int4*   tp = (const int4*)(term + nbase);
                #pragma unroll
                for (int q = 0; q < IPTC / 4; ++q) {
                    bR[(c - 1) & 1][q] = rp[q];
                    bT[(c - 1) & 1][q] = tp[q];
                }
            }
            const int p = c & 1;
            const long long base = lo + (long long)c * CHUNK + (long long)t * IPTC;

            float r[IPTC];
            unsigned mask = 0;
            #pragma unroll
            for (int q = 0; q < IPTC / 4; ++q) {
                float4 rv = bR[p][q];
                int4   tv = bT[p][q];
                r[4*q+0] = rv.x; r[4*q+1] = rv.y; r[4*q+2] = rv.z; r[4*q+3] = rv.w;
                mask |= (tv.x ? 1u : 0u) << (4*q+0);
                mask |= (tv.y ? 1u : 0u) << (4*q+1);
                mask |= (tv.z ? 1u : 0u) << (4*q+2);
                mask |= (tv.w ? 1u : 0u) << (4*q+3);
            }

            // thread-local compose, high->low
            float A = 1.f, B = 0.f;
            #pragma unroll
            for (int k = IPTC - 1; k >= 0; --k) {
                float ak = ((mask >> k) & 1u) ? 0.f : DISC;
                B = ak * B + r[k]; A = ak * A;
            }

            float IA = A, IB = B;
            wave_suffix_scan(IA, IB, lane);

            int myLast = mask ? (int)(base + (31 - __clz(mask))) : -1;
            #pragma unroll
            for (int off = 32; off > 0; off >>= 1)
                myLast = max(myLast, __shfl_down(myLast, off, 64));

            if (lane == 0) { sWA[wav] = make_float2(IA, IB); sLast[wav] = myLast; }
            __syncthreads();

            // chunk aggregate + exclusives (all threads, redundant & cheap)
            float2 g = sWA[0];
            int cl = sLast[0];
            #pragma unroll
            for (int w = 1; w < TPB / 64; ++w) {
                float2 h = sWA[w];
                g.y = g.x * h.y + g.y; g.x = g.x * h.x;
                cl = max(cl, sLast[w]);
            }
            float EWA = 1.f, EWB = 0.f;
            #pragma unroll
            for (int w = 0; w < TPB / 64; ++w)
                if (w > wav) { float2 h = sWA[w]; EWB = EWA*h.y + EWB; EWA = EWA*h.x; }

            float EA = __shfl_down(IA, 1, 64);
            float EB = __shfl_down(IB, 1, 64);
            if (lane == 63) { EA = 1.f; EB = 0.f; }

            const float Yc = Bt;              // y entering this chunk from above
            float y = EA * (EWA * Yc + EWB) + EB;

            #pragma unroll
            for (int k = IPTC - 1; k >= 0; --k) {
                float ak = ((mask >> k) & 1u) ? 0.f : DISC;
                y = ak * y + r[k]; r[k] = y;
            }

            float4* op = (float4*)(out + base);
            #pragma unroll
            for (int q = 0; q < IPTC / 4; ++q)
                op[q] = make_float4(r[4*q+0], r[4*q+1], r[4*q+2], r[4*q+3]);

            // fold chunk into block aggregate: F_new = F_c o F_prev
            Bt = g.x * Bt + g.y;
            At = g.x * At;
            lt = max(lt, cl);
            __syncthreads();   // protect sWA/sLast reuse next chunk
        }
    } else {
        // guarded tail block (only the last block when T % TILE != 0)
        for (int c = NCH - 1; c >= 0; --c) {
            const long long base = lo + (long long)c * CHUNK + (long long)t * IPTC;
            float r[IPTC];
            unsigned mask = 0;
            #pragma unroll
            for (int k = 0; k < IPTC; ++k) {
                long long i = base + k;
                if (i < T) { r[k] = rew[i]; mask |= (term[i] ? 1u : 0u) << k; }
                else       { r[k] = 0.f; }
            }
            float A = 1.f, B = 0.f;
            #pragma unroll
            for (int k = IPTC - 1; k >= 0; --k) {
                float ak = ((mask >> k) & 1u) ? 0.f : DISC;
                if (base + k >= T) ak = 1.f;
                B = ak * B + r[k]; A = ak * A;
            }
            float IA = A, IB = B;
            wave_suffix_scan(IA, IB, lane);

            int myLast = mask ? (int)(base + (31 - __clz(mask))) : -1;
            #pragma unroll
            for (int off = 32; off > 0; off >>= 1)
                myLast = max(myLast, __shfl_down(myLast, off, 64));

            if (lane == 0) { sWA[wav] = make_float2(IA, IB); sLast[wav] = myLast; }
            __syncthreads();

            float2 g = sWA[0];
            int cl = sLast[0];
            #pragma unroll
            for (int w = 1; w < TPB / 64; ++w) {
                float2 h = sWA[w];
                g.y = g.x * h.y + g.y; g.x = g.x * h.x;
                cl = max(cl, sLast[w]);
            }
            float EWA = 1.f, EWB = 0.f;
            #pragma unroll
            for (int w = 0; w < TPB / 64; ++w)
                if (w > wav) { float2 h = sWA[w]; EWB = EWA*h.y + EWB; EWA = EWA*h.x; }

            float EA = __shfl_down(IA, 1, 64);
            float EB = __shfl_down(IB, 1, 64);
            if (lane == 63) { EA = 1.f; EB = 0.f; }

            const float Yc = Bt;
            float y = EA * (EWA * Yc + EWB) + EB;

            #pragma unroll
            for (int k = IPTC - 1; k >= 0; --k) {
                float ak = ((mask >> k) & 1u) ? 0.f : DISC;
                if (base + k >= T) ak = 1.f;
                y = ak * y + r[k]; r[k] = y;
            }
            #pragma unroll
            for (int k = 0; k < IPTC; ++k) {
                long long i = base + k;
                if (i < T) out[i] = r[k];
            }

            Bt = g.x * Bt + g.y;
            At = g.x * At;
            lt = max(lt, cl);
            __syncthreads();
        }
    }

    if (t == 0) {
        agg[b] = make_float2(At, Bt);
        lastT[b] = max(lt, (int)lo - 1);   // lo-1 == "no terminal in block"
    }
}

// K2: per-block y_in from aggregates above, then sparse tail correction.
__global__ __launch_bounds__(TPB) void k_fix(
        const float2* __restrict__ agg, const int* __restrict__ lastT,
        float* __restrict__ out, int numBlocks, long long T) {
    __shared__ float2 sWB[TPB / 64];

    const int t = threadIdx.x;
    const int lane = t & 63, wav = t >> 6;
    const int b = blockIdx.x;

    const int cpt = (numBlocks + TPB - 1) / TPB;     // 8 for 2048
    float VA = 1.f, VB = 0.f;
    #pragma unroll
    for (int k = cpt - 1; k >= 0; --k) {             // descending g: inner first
        int g = t * cpt + k;
        if (g > b && g < numBlocks) {
            float2 q = agg[g];
            VB = q.x * VB + q.y; VA = q.x * VA;
        }
    }
    wave_suffix_scan(VA, VB, lane);
    if (lane == 0) sWB[wav] = make_float2(VA, VB);
    __syncthreads();

    float FA = sWB[0].x, FB = sWB[0].y;              // wave 0 outermost
    #pragma unroll
    for (int w = 1; w < TPB / 64; ++w) {
        float2 h = sWB[w];
        FB = FA * h.y + FB; FA = FA * h.x;
    }
    const float yin = FB;                            // y entering block b (x=0)
    if (yin == 0.f) return;

    const long long lo = (long long)b * TILE;
    const long long hi = min(lo + TILE, T) - 1;
    const long long start = (long long)lastT[b] + 1; // >= lo by construction

    for (long long i = start + t; i <= hi; i += TPB) {
        float d = (float)(int)(hi + 1 - i);
        out[i] += exp2f(d * L2DISC) * yin;
    }
}

extern "C" void kernel_launch(void* const* d_in, const int* in_sizes, int n_in,
                              void* d_out, int out_size, void* d_ws, size_t ws_size,
                              hipStream_t stream) {
    const int*   term = (const int*)d_in[0];
    const float* rew  = (const float*)d_in[1];
    float*       out  = (float*)d_out;

    const long long T = (long long)in_sizes[1];
    const int numBlocks = (int)((T + TILE - 1) / TILE);   // 2048 for T=2^24

    float2* agg   = (float2*)d_ws;
    int*    lastT = (int*)(agg + numBlocks);

    k_local<<<numBlocks, TPB, 0, stream>>>(term, rew, out, agg, lastT, T);
    k_fix  <<<numBlocks, TPB, 0, stream>>>(agg, lastT, out, numBlocks, T);
}